// Round 4
// baseline (425.555 us; speedup 1.0000x reference)
//
#include <hip/hip_runtime.h>
#include <hip/hip_bf16.h>

// Problem constants
#define B_ 2
#define S_ 2048
#define D_ 1024
#define H_ 16
#define P_ 2048
#define T_ 4096   // P_ + S_
#define DEPTH_ 64

typedef __bf16 bf16x8 __attribute__((ext_vector_type(8)));
typedef float  f32x4  __attribute__((ext_vector_type(4)));
typedef short  short8_t __attribute__((ext_vector_type(8)));
typedef unsigned short ushort_t;
typedef unsigned short ushort4_t __attribute__((ext_vector_type(4)));

// f32 -> bf16 round-to-nearest-even
__device__ __forceinline__ ushort_t f2bf(float f) {
    union { float f; unsigned u; } v; v.f = f;
    return (ushort_t)((v.u + 0x7fffu + ((v.u >> 16) & 1u)) >> 16);
}

__device__ __forceinline__ void gload16(const void* g, void* l) {
    __builtin_amdgcn_global_load_lds(
        (const __attribute__((address_space(1))) unsigned int*)g,
        (__attribute__((address_space(3))) unsigned int*)l, 16, 0, 0);
}

// =====================================================================
// x [4096][1024] f32 -> bf16
// =====================================================================
__global__ __launch_bounds__(256)
void convert_bf16_kernel(const float4* __restrict__ in, ushort4_t* __restrict__ out, int n4)
{
    for (int i = blockIdx.x * 256 + threadIdx.x; i < n4; i += gridDim.x * 256) {
        float4 v = in[i];
        ushort4_t o;
        o[0] = f2bf(v.x); o[1] = f2bf(v.y); o[2] = f2bf(v.z); o[3] = f2bf(v.w);
        out[i] = o;
    }
}

// =====================================================================
// w [K=1024][N] f32 -> wt [N][1024] bf16 (transposed)
// =====================================================================
__global__ __launch_bounds__(256)
void transpose_conv_kernel(const float* __restrict__ w, ushort_t* __restrict__ wt, int N)
{
    __shared__ float t[64][65];
    const int tid = threadIdx.x;
    const int k0 = blockIdx.y * 64, n0 = blockIdx.x * 64;
    #pragma unroll
    for (int rep = 0; rep < 4; ++rep) {
        const int idx = rep * 256 + tid;
        const int r = idx >> 4, c = idx & 15;
        float4 v = *(const float4*)&w[(size_t)(k0 + r) * N + n0 + c * 4];
        t[r][c*4+0] = v.x; t[r][c*4+1] = v.y; t[r][c*4+2] = v.z; t[r][c*4+3] = v.w;
    }
    __syncthreads();
    #pragma unroll
    for (int rep = 0; rep < 4; ++rep) {
        const int idx = rep * 256 + tid;
        const int nl = idx >> 4, kg = idx & 15;
        ushort4_t o;
        o[0] = f2bf(t[kg*4+0][nl]); o[1] = f2bf(t[kg*4+1][nl]);
        o[2] = f2bf(t[kg*4+2][nl]); o[3] = f2bf(t[kg*4+3][nl]);
        *(ushort4_t*)&wt[(size_t)(n0 + nl) * 1024 + k0 + kg*4] = o;
    }
}

// =====================================================================
// bf16 MFMA GEMM (m97 structure) — unchanged from round 3 (verified).
// =====================================================================
template<int MODE>
__global__ __launch_bounds__(256)
void gemm_bf16_kernel(const ushort_t* __restrict__ A,
                      const ushort_t* __restrict__ Bt,
                      const float*  __restrict__ bias,
                      ushort_t* __restrict__ out_qb,
                      float*  __restrict__ out_present,
                      float*  __restrict__ out_plain)
{
    __shared__ __attribute__((aligned(16))) ushort_t As[128*32];
    __shared__ __attribute__((aligned(16))) ushort_t Bs[128*32];

    const int tid  = threadIdx.x;
    const int w    = tid >> 6;
    const int lane = tid & 63;
    const int g    = lane >> 4;
    const int ln   = lane & 15;
    const int wr   = w >> 1, wc = w & 1;
    const int row0 = blockIdx.y * 128;
    const int col0 = blockIdx.x * 128;

    int srow[2], sgl[2];
    #pragma unroll
    for (int r = 0; r < 2; ++r) {
        const int o = (w*2 + r) * 1024 + lane * 16;
        srow[r] = o >> 6;
        const int gp = (o >> 4) & 3;
        sgl[r] = gp ^ ((srow[r] >> 1) & 3);
    }

    f32x4 acc[4][4];
    #pragma unroll
    for (int i = 0; i < 4; ++i)
        #pragma unroll
        for (int j = 0; j < 4; ++j)
            acc[i][j] = (f32x4){0.f, 0.f, 0.f, 0.f};

    for (int k0 = 0; k0 < 1024; k0 += 32) {
        #pragma unroll
        for (int r = 0; r < 2; ++r) {
            const int lb = (w*2 + r) * 512;
            gload16(&A [(size_t)(row0 + srow[r]) * 1024 + k0 + sgl[r]*8], &As[lb]);
            gload16(&Bt[(size_t)(col0 + srow[r]) * 1024 + k0 + sgl[r]*8], &Bs[lb]);
        }
        __syncthreads();

        bf16x8 af[4], bfr[4];
        #pragma unroll
        for (int i = 0; i < 4; ++i) {
            const int ra = wr*64 + i*16 + ln;
            const int ga = g ^ ((ra >> 1) & 3);
            af[i] = __builtin_bit_cast(bf16x8, *(const short8_t*)&As[ra*32 + ga*8]);
            const int rb = wc*64 + i*16 + ln;
            const int gb = g ^ ((rb >> 1) & 3);
            bfr[i] = __builtin_bit_cast(bf16x8, *(const short8_t*)&Bs[rb*32 + gb*8]);
        }
        #pragma unroll
        for (int i = 0; i < 4; ++i)
            #pragma unroll
            for (int j = 0; j < 4; ++j)
                acc[i][j] = __builtin_amdgcn_mfma_f32_16x16x32_bf16(af[i], bfr[j], acc[i][j], 0, 0, 0);
        __syncthreads();
    }

    #pragma unroll
    for (int i = 0; i < 4; ++i) {
        #pragma unroll
        for (int j = 0; j < 4; ++j) {
            const int rm = row0 + wr*64 + i*16 + g*4 + j;
            const int b  = rm >> 11;
            const int s  = rm & 2047;
            #pragma unroll
            for (int jn = 0; jn < 4; ++jn) {
                const int e = col0 + wc*64 + jn*16 + ln;
                const float v = acc[i][jn][j] + bias[e];
                if (MODE == 0) {
                    const int which = e >> 10;
                    const int f = e & 1023;
                    const int h = f >> 6, d = f & 63;
                    if (which == 0) {
                        out_qb[(size_t)(((b*16 + h) * 2048 + s) << 6) + d] = f2bf(v);
                    } else {
                        const int kv = which - 1;
                        out_present[((((size_t)(b*2 + kv)*16 + h) * 4096 + 2048 + s) << 6) + d] = v;
                    }
                } else {
                    out_plain[(size_t)rm * 1024 + e] = v;
                }
            }
        }
    }
}

// =====================================================================
// past_layer [B,2,H,P,64] -> present[b,kv,h,0:P,:]  (fp32 linear)
// =====================================================================
__global__ __launch_bounds__(256)
void copy_past_kernel(const float4* __restrict__ past, float4* __restrict__ present4)
{
    const int idx = blockIdx.x * 256 + threadIdx.x;
    if (idx >= (B_*2*H_*P_*DEPTH_)/4) return;
    const int c = idx >> 15;
    const int r = idx & 32767;
    present4[(size_t)c * (T_*DEPTH_/4) + r] = past[idx];
}

// =====================================================================
// present f32 -> K_ws bf16 [bh][T][64] (linear) + V_ws bf16 [bh][64][T]
// (transposed). One block = one (bh, 64-key tile).
// =====================================================================
__global__ __launch_bounds__(256)
void prep_kv_kernel(const float* __restrict__ present,
                    ushort_t* __restrict__ Kws, ushort_t* __restrict__ Vws)
{
    __shared__ float tv[64][65];
    const int tid = threadIdx.x;
    const int kt  = blockIdx.x;       // 0..63 key tile
    const int bh  = blockIdx.y;       // 0..31
    const int b   = bh >> 4, h = bh & 15;

    const float* Kp = present + (((size_t)(b*2 + 0)*16 + h) * T_ + kt*64) * 64;
    const float* Vp = present + (((size_t)(b*2 + 1)*16 + h) * T_ + kt*64) * 64;
    ushort_t* Kd = Kws + ((size_t)bh * T_ + kt*64) * 64;

    #pragma unroll
    for (int rep = 0; rep < 4; ++rep) {
        const int idx = rep * 256 + tid;          // 0..1023 float4s
        float4 v = ((const float4*)Kp)[idx];
        ushort4_t o;
        o[0] = f2bf(v.x); o[1] = f2bf(v.y); o[2] = f2bf(v.z); o[3] = f2bf(v.w);
        *(ushort4_t*)&Kd[idx*4] = o;
        // V into LDS
        const int r = idx >> 4, c = idx & 15;
        float4 vv = *(const float4*)&Vp[(size_t)r * 64 + c * 4];
        tv[r][c*4+0] = vv.x; tv[r][c*4+1] = vv.y;
        tv[r][c*4+2] = vv.z; tv[r][c*4+3] = vv.w;
    }
    __syncthreads();
    #pragma unroll
    for (int rep = 0; rep < 4; ++rep) {
        const int idx = rep * 256 + tid;
        const int d = idx >> 4, pg = idx & 15;
        ushort4_t o;
        o[0] = f2bf(tv[pg*4+0][d]); o[1] = f2bf(tv[pg*4+1][d]);
        o[2] = f2bf(tv[pg*4+2][d]); o[3] = f2bf(tv[pg*4+3][d]);
        *(ushort4_t*)&Vws[((size_t)bh*64 + d) * T_ + kt*64 + pg*4] = o;
    }
}

// =====================================================================
// Flash attention v2: QBLOCK=128 (4 waves x 32 q rows), KVBLK=64,
// double-buffered global_load_lds staging (swizzled source, T2/m173),
// 1 raw barrier/tile + counted vmcnt, defer-max (T13), XCD swizzle (T1).
// =====================================================================
__global__ __launch_bounds__(256)
void attn_v2_kernel(const ushort_t* __restrict__ qin,   // [B,H,S,64] bf16
                    const ushort_t* __restrict__ Kws,   // [bh][T][64] bf16
                    const ushort_t* __restrict__ Vws,   // [bh][64][T] bf16
                    ushort_t* __restrict__ merged)      // [B,S,D] bf16
{
    __shared__ __attribute__((aligned(16))) ushort_t Kb[2][4096];
    __shared__ __attribute__((aligned(16))) ushort_t Vb[2][4096];
    __shared__ __attribute__((aligned(16))) ushort_t Pb[4][2048];

    const int tid  = threadIdx.x;
    const int w    = tid >> 6;
    const int lane = tid & 63;
    const int g    = lane >> 4;
    const int ln   = lane & 15;
    const int lsub = lane >> 3;                 // 0..7 (row&7 of staged row)
    const int swz8 = ((lane & 7) ^ lsub) * 8;   // swizzled granule, ushorts

    // XCD-chunked swizzle: 512 blocks, 8 XCDs -> 4 bh per XCD; long-first.
    const int bid = (int)blockIdx.x;
    const int wg  = (bid & 7) * 64 + (bid >> 3);
    const int bh  = wg >> 4;
    const int q0  = (15 - (wg & 15)) * 128;
    const int b   = bh >> 4, h = bh & 15;

    const ushort_t* Kbase = Kws + (size_t)bh * T_ * 64;
    const ushort_t* Vbase = Vws + (size_t)bh * 64 * T_;

    const int nt = 34 + q0 / 64;

    // prologue: stage tile 0 into buf 0 (4 gloads/wave)
    {
        const int t0 = 0;
        #pragma unroll
        for (int rep = 0; rep < 2; ++rep) {
            const int i = w*2 + rep;
            gload16(Kbase + (((size_t)t0 + i*8 + lsub) << 6) + swz8, &Kb[0][i*512]);
            gload16(Vbase + (size_t)(i*8 + lsub) * T_ + t0 + swz8,   &Vb[0][i*512]);
        }
    }

    // Q fragments: qf[rf][dh], row = q0 + w*32 + rf*16 + ln
    bf16x8 qf[2][2];
    #pragma unroll
    for (int rf = 0; rf < 2; ++rf) {
        const ushort_t* Qr = qin + ((size_t)bh * S_ + q0 + w*32 + rf*16 + ln) * 64;
        #pragma unroll
        for (int dh = 0; dh < 2; ++dh)
            qf[rf][dh] = __builtin_bit_cast(bf16x8, *(const short8_t*)(Qr + dh*32 + g*8));
    }

    f32x4 o[2][4];
    float m_r[2][4], l_r[2][4];
    #pragma unroll
    for (int rf = 0; rf < 2; ++rf) {
        #pragma unroll
        for (int r = 0; r < 4; ++r) { m_r[rf][r] = -3.0e38f; l_r[rf][r] = 0.f; }
        #pragma unroll
        for (int d = 0; d < 4; ++d) o[rf][d] = (f32x4){0.f, 0.f, 0.f, 0.f};
    }

    int buf = 0;
    for (int t = 0; t < nt; ++t) {
        asm volatile("s_waitcnt vmcnt(0)" ::: "memory");   // own loads for tile t done
        __builtin_amdgcn_s_barrier();                      // all waves' tile-t data in LDS
        __builtin_amdgcn_sched_barrier(0);

        if (t + 1 < nt) {                                  // stage t+1 into other buffer
            const int t0n = (t + 1) * 64;
            #pragma unroll
            for (int rep = 0; rep < 2; ++rep) {
                const int i = w*2 + rep;
                gload16(Kbase + (((size_t)t0n + i*8 + lsub) << 6) + swz8, &Kb[buf^1][i*512]);
                gload16(Vbase + (size_t)(i*8 + lsub) * T_ + t0n + swz8,   &Vb[buf^1][i*512]);
            }
            __builtin_amdgcn_sched_barrier(0);
        }

        // ---- QK^T ----
        f32x4 s[2][4];
        #pragma unroll
        for (int js = 0; js < 4; ++js) {
            const ushort_t* kr = &Kb[buf][(js*16 + ln) * 64];
            bf16x8 k0 = __builtin_bit_cast(bf16x8, *(const short8_t*)(kr + ((g    ) ^ (ln&7))*8));
            bf16x8 k1 = __builtin_bit_cast(bf16x8, *(const short8_t*)(kr + ((4 + g) ^ (ln&7))*8));
            #pragma unroll
            for (int rf = 0; rf < 2; ++rf) {
                f32x4 z = (f32x4){0.f, 0.f, 0.f, 0.f};
                z = __builtin_amdgcn_mfma_f32_16x16x32_bf16(qf[rf][0], k0, z, 0, 0, 0);
                z = __builtin_amdgcn_mfma_f32_16x16x32_bf16(qf[rf][1], k1, z, 0, 0, 0);
                s[rf][js] = z;
            }
        }

        // ---- scale (+mask on last two tiles) + row max ----
        float mx[2][4];
        const int off = t*64 - q0 - 2048;     // mask iff key_local + off > qrow_rel
        if (t >= nt - 2) {
            #pragma unroll
            for (int rf = 0; rf < 2; ++rf)
                #pragma unroll
                for (int r = 0; r < 4; ++r) {
                    const int qrow = w*32 + rf*16 + g*4 + r;
                    #pragma unroll
                    for (int js = 0; js < 4; ++js) {
                        float v = s[rf][js][r] * 0.125f;
                        if (js*16 + ln + off > qrow) v = -1e30f;
                        s[rf][js][r] = v;
                    }
                }
        } else {
            #pragma unroll
            for (int rf = 0; rf < 2; ++rf)
                #pragma unroll
                for (int r = 0; r < 4; ++r)
                    #pragma unroll
                    for (int js = 0; js < 4; ++js)
                        s[rf][js][r] *= 0.125f;
        }
        #pragma unroll
        for (int rf = 0; rf < 2; ++rf)
            #pragma unroll
            for (int r = 0; r < 4; ++r) {
                float v = fmaxf(fmaxf(s[rf][0][r], s[rf][1][r]),
                                fmaxf(s[rf][2][r], s[rf][3][r]));
                v = fmaxf(v, __shfl_xor(v, 1));
                v = fmaxf(v, __shfl_xor(v, 2));
                v = fmaxf(v, __shfl_xor(v, 4));
                v = fmaxf(v, __shfl_xor(v, 8));
                mx[rf][r] = v;
            }

        // ---- defer-max decision (wave-uniform) ----
        bool ok = true;
        #pragma unroll
        for (int rf = 0; rf < 2; ++rf)
            #pragma unroll
            for (int r = 0; r < 4; ++r)
                ok = ok && (mx[rf][r] <= m_r[rf][r] + 8.0f);

        if (__all(ok)) {
            // no rescale: exp against old running max
            #pragma unroll
            for (int rf = 0; rf < 2; ++rf)
                #pragma unroll
                for (int r = 0; r < 4; ++r) {
                    const int prow = rf*16 + g*4 + r;
                    float rs = 0.f;
                    #pragma unroll
                    for (int js = 0; js < 4; ++js) {
                        const float p = __expf(s[rf][js][r] - m_r[rf][r]);
                        rs += p;
                        Pb[w][prow*64 + (((js*2) + (ln>>3)) ^ (prow&7))*8 + (ln&7)] = f2bf(p);
                    }
                    rs += __shfl_xor(rs, 1);
                    rs += __shfl_xor(rs, 2);
                    rs += __shfl_xor(rs, 4);
                    rs += __shfl_xor(rs, 8);
                    l_r[rf][r] += rs;
                }
        } else {
            #pragma unroll
            for (int rf = 0; rf < 2; ++rf)
                #pragma unroll
                for (int r = 0; r < 4; ++r) {
                    const int prow = rf*16 + g*4 + r;
                    const float mnew = fmaxf(m_r[rf][r], mx[rf][r]);
                    const float corr = __expf(m_r[rf][r] - mnew);
                    m_r[rf][r] = mnew;
                    float rs = 0.f;
                    #pragma unroll
                    for (int js = 0; js < 4; ++js) {
                        const float p = __expf(s[rf][js][r] - mnew);
                        rs += p;
                        Pb[w][prow*64 + (((js*2) + (ln>>3)) ^ (prow&7))*8 + (ln&7)] = f2bf(p);
                    }
                    rs += __shfl_xor(rs, 1);
                    rs += __shfl_xor(rs, 2);
                    rs += __shfl_xor(rs, 4);
                    rs += __shfl_xor(rs, 8);
                    l_r[rf][r] = l_r[rf][r] * corr + rs;
                    #pragma unroll
                    for (int d = 0; d < 4; ++d) o[rf][d][r] *= corr;
                }
        }

        // ---- PV ----
        #pragma unroll
        for (int ks = 0; ks < 2; ++ks) {
            const int pg = ((ks*4 + g) ^ (ln & 7)) * 8;
            bf16x8 pa0 = __builtin_bit_cast(bf16x8, *(const short8_t*)&Pb[w][(     ln)*64 + pg]);
            bf16x8 pa1 = __builtin_bit_cast(bf16x8, *(const short8_t*)&Pb[w][(16 + ln)*64 + pg]);
            #pragma unroll
            for (int dsub = 0; dsub < 4; ++dsub) {
                bf16x8 vb = __builtin_bit_cast(bf16x8,
                              *(const short8_t*)&Vb[buf][(dsub*16 + ln)*64 + pg]);
                o[0][dsub] = __builtin_amdgcn_mfma_f32_16x16x32_bf16(pa0, vb, o[0][dsub], 0, 0, 0);
                o[1][dsub] = __builtin_amdgcn_mfma_f32_16x16x32_bf16(pa1, vb, o[1][dsub], 0, 0, 0);
            }
        }

        buf ^= 1;
    }

    // ---- epilogue ----
    #pragma unroll
    for (int rf = 0; rf < 2; ++rf)
        #pragma unroll
        for (int r = 0; r < 4; ++r) {
            const float inv = 1.f / l_r[rf][r];
            const int row = q0 + w*32 + rf*16 + g*4 + r;
            ushort_t* outp = &merged[((size_t)b * S_ + row) * D_ + h*64 + ln];
            #pragma unroll
            for (int dsub = 0; dsub < 4; ++dsub)
                outp[dsub*16] = f2bf(o[rf][dsub][r] * inv);
        }
}

// =====================================================================
extern "C" void kernel_launch(void* const* d_in, const int* in_sizes, int n_in,
                              void* d_out, int out_size, void* d_ws, size_t ws_size,
                              hipStream_t stream)
{
    const float* x      = (const float*)d_in[0];
    // d_in[1] = mask: causal structure computed analytically, never read
    const float* past   = (const float*)d_in[2];
    const float* w_attn = (const float*)d_in[3];
    const float* b_attn = (const float*)d_in[4];
    const float* w_proj = (const float*)d_in[5];
    const float* b_proj = (const float*)d_in[6];

    float* out     = (float*)d_out;                    // [B,S,D]
    float* present = out + (size_t)B_ * S_ * D_;       // [B,2,H,T,64]

    // ws layout (bytes):
    //  [ 0, 8M)  q_ws      (alive: gemm0 -> attn)
    //  [ 8,16M)  mergedb   (attn -> gemm1)
    //  [16,18M)  wptb      (prep -> gemm1)
    //  [18,26M)  xb        (prep -> gemm0)   } overlaid by K_ws after gemm0
    //  [26,32M)  watb      (prep -> gemm0)   }
    //  [18,34M)  K_ws      (prep_kv -> attn)
    //  [34,50M)  V_ws      (prep_kv -> attn)
    ushort_t* wsu     = (ushort_t*)d_ws;
    ushort_t* q_ws    = wsu;
    ushort_t* mergedb = wsu + 4194304;
    ushort_t* wptb    = wsu + 8388608;
    ushort_t* xb      = wsu + 9437184;
    ushort_t* watb    = wsu + 13631488;
    ushort_t* K_ws    = wsu + 9437184;    // overlays xb+watb (dead after gemm0)
    ushort_t* V_ws    = wsu + 17825792;

    // 0) prep: convert x, transpose-convert weights
    convert_bf16_kernel<<<2048, 256, 0, stream>>>(
        (const float4*)x, (ushort4_t*)xb, (B_*S_*D_)/4);
    transpose_conv_kernel<<<dim3(48, 16), 256, 0, stream>>>(w_attn, watb, 3072);
    transpose_conv_kernel<<<dim3(16, 16), 256, 0, stream>>>(w_proj, wptb, 1024);

    // 1) QKV projection; q -> bf16 ws, k/v -> present f32
    gemm_bf16_kernel<0><<<dim3(24, 32), 256, 0, stream>>>(
        xb, watb, b_attn, q_ws, present, nullptr);

    // 2) past -> present (rows 0..P-1)
    copy_past_kernel<<<dim3((B_*2*H_*P_*DEPTH_/4 + 255)/256), 256, 0, stream>>>(
        (const float4*)past, (float4*)present);

    // 3) present -> bf16 K_ws (linear) + V_ws (transposed)
    prep_kv_kernel<<<dim3(64, 32), 256, 0, stream>>>(present, K_ws, V_ws);

    // 4) flash attention v2 -> merged bf16
    attn_v2_kernel<<<dim3(512), 256, 0, stream>>>(q_ws, K_ws, V_ws, mergedb);

    // 5) output projection
    gemm_bf16_kernel<1><<<dim3(8, 32), 256, 0, stream>>>(
        mergedb, wptb, b_proj, nullptr, nullptr, out);
}

// Round 5
// 245.829 us; speedup vs baseline: 1.7311x; 1.7311x over previous
//
#include <hip/hip_runtime.h>
#include <hip/hip_bf16.h>

// Problem constants
#define B_ 2
#define S_ 2048
#define D_ 1024
#define H_ 16
#define P_ 2048
#define T_ 4096   // P_ + S_
#define DEPTH_ 64

typedef __bf16 bf16x8 __attribute__((ext_vector_type(8)));
typedef float  f32x4  __attribute__((ext_vector_type(4)));
typedef short  short8_t __attribute__((ext_vector_type(8)));
typedef unsigned short ushort_t;
typedef unsigned short ushort4_t __attribute__((ext_vector_type(4)));

// f32 -> bf16 round-to-nearest-even
__device__ __forceinline__ ushort_t f2bf(float f) {
    union { float f; unsigned u; } v; v.f = f;
    return (ushort_t)((v.u + 0x7fffu + ((v.u >> 16) & 1u)) >> 16);
}

__device__ __forceinline__ void gload16(const void* g, void* l) {
    __builtin_amdgcn_global_load_lds(
        (const __attribute__((address_space(1))) unsigned int*)g,
        (__attribute__((address_space(3))) unsigned int*)l, 16, 0, 0);
}

// =====================================================================
// x [4096][1024] f32 -> bf16
// =====================================================================
__global__ __launch_bounds__(256)
void convert_bf16_kernel(const float4* __restrict__ in, ushort4_t* __restrict__ out, int n4)
{
    for (int i = blockIdx.x * 256 + threadIdx.x; i < n4; i += gridDim.x * 256) {
        float4 v = in[i];
        ushort4_t o;
        o[0] = f2bf(v.x); o[1] = f2bf(v.y); o[2] = f2bf(v.z); o[3] = f2bf(v.w);
        out[i] = o;
    }
}

// =====================================================================
// w [K=1024][N] f32 -> wt [N][1024] bf16 (transposed)
// =====================================================================
__global__ __launch_bounds__(256)
void transpose_conv_kernel(const float* __restrict__ w, ushort_t* __restrict__ wt, int N)
{
    __shared__ float t[64][65];
    const int tid = threadIdx.x;
    const int k0 = blockIdx.y * 64, n0 = blockIdx.x * 64;
    #pragma unroll
    for (int rep = 0; rep < 4; ++rep) {
        const int idx = rep * 256 + tid;
        const int r = idx >> 4, c = idx & 15;
        float4 v = *(const float4*)&w[(size_t)(k0 + r) * N + n0 + c * 4];
        t[r][c*4+0] = v.x; t[r][c*4+1] = v.y; t[r][c*4+2] = v.z; t[r][c*4+3] = v.w;
    }
    __syncthreads();
    #pragma unroll
    for (int rep = 0; rep < 4; ++rep) {
        const int idx = rep * 256 + tid;
        const int nl = idx >> 4, kg = idx & 15;
        ushort4_t o;
        o[0] = f2bf(t[kg*4+0][nl]); o[1] = f2bf(t[kg*4+1][nl]);
        o[2] = f2bf(t[kg*4+2][nl]); o[3] = f2bf(t[kg*4+3][nl]);
        *(ushort4_t*)&wt[(size_t)(n0 + nl) * 1024 + k0 + kg*4] = o;
    }
}

// =====================================================================
// bf16 MFMA GEMM (m97 structure). MODE 0 now scales q by 1/sqrt(64).
// =====================================================================
template<int MODE>
__global__ __launch_bounds__(256)
void gemm_bf16_kernel(const ushort_t* __restrict__ A,
                      const ushort_t* __restrict__ Bt,
                      const float*  __restrict__ bias,
                      ushort_t* __restrict__ out_qb,
                      float*  __restrict__ out_present,
                      float*  __restrict__ out_plain)
{
    __shared__ __attribute__((aligned(16))) ushort_t As[128*32];
    __shared__ __attribute__((aligned(16))) ushort_t Bs[128*32];

    const int tid  = threadIdx.x;
    const int w    = tid >> 6;
    const int lane = tid & 63;
    const int g    = lane >> 4;
    const int ln   = lane & 15;
    const int wr   = w >> 1, wc = w & 1;
    const int row0 = blockIdx.y * 128;
    const int col0 = blockIdx.x * 128;

    int srow[2], sgl[2];
    #pragma unroll
    for (int r = 0; r < 2; ++r) {
        const int o = (w*2 + r) * 1024 + lane * 16;
        srow[r] = o >> 6;
        const int gp = (o >> 4) & 3;
        sgl[r] = gp ^ ((srow[r] >> 1) & 3);
    }

    f32x4 acc[4][4];
    #pragma unroll
    for (int i = 0; i < 4; ++i)
        #pragma unroll
        for (int j = 0; j < 4; ++j)
            acc[i][j] = (f32x4){0.f, 0.f, 0.f, 0.f};

    for (int k0 = 0; k0 < 1024; k0 += 32) {
        #pragma unroll
        for (int r = 0; r < 2; ++r) {
            const int lb = (w*2 + r) * 512;
            gload16(&A [(size_t)(row0 + srow[r]) * 1024 + k0 + sgl[r]*8], &As[lb]);
            gload16(&Bt[(size_t)(col0 + srow[r]) * 1024 + k0 + sgl[r]*8], &Bs[lb]);
        }
        __syncthreads();

        bf16x8 af[4], bfr[4];
        #pragma unroll
        for (int i = 0; i < 4; ++i) {
            const int ra = wr*64 + i*16 + ln;
            const int ga = g ^ ((ra >> 1) & 3);
            af[i] = __builtin_bit_cast(bf16x8, *(const short8_t*)&As[ra*32 + ga*8]);
            const int rb = wc*64 + i*16 + ln;
            const int gb = g ^ ((rb >> 1) & 3);
            bfr[i] = __builtin_bit_cast(bf16x8, *(const short8_t*)&Bs[rb*32 + gb*8]);
        }
        #pragma unroll
        for (int i = 0; i < 4; ++i)
            #pragma unroll
            for (int j = 0; j < 4; ++j)
                acc[i][j] = __builtin_amdgcn_mfma_f32_16x16x32_bf16(af[i], bfr[j], acc[i][j], 0, 0, 0);
        __syncthreads();
    }

    #pragma unroll
    for (int i = 0; i < 4; ++i) {
        #pragma unroll
        for (int j = 0; j < 4; ++j) {
            const int rm = row0 + wr*64 + i*16 + g*4 + j;
            const int b  = rm >> 11;
            const int s  = rm & 2047;
            #pragma unroll
            for (int jn = 0; jn < 4; ++jn) {
                const int e = col0 + wc*64 + jn*16 + ln;
                const float v = acc[i][jn][j] + bias[e];
                if (MODE == 0) {
                    const int which = e >> 10;
                    const int f = e & 1023;
                    const int h = f >> 6, d = f & 63;
                    if (which == 0) {
                        // fold 1/sqrt(depth) into q
                        out_qb[(size_t)(((b*16 + h) * 2048 + s) << 6) + d] = f2bf(v * 0.125f);
                    } else {
                        const int kv = which - 1;
                        out_present[((((size_t)(b*2 + kv)*16 + h) * 4096 + 2048 + s) << 6) + d] = v;
                    }
                } else {
                    out_plain[(size_t)rm * 1024 + e] = v;
                }
            }
        }
    }
}

// =====================================================================
// past_layer [B,2,H,P,64] -> present[b,kv,h,0:P,:]  (fp32 linear)
// =====================================================================
__global__ __launch_bounds__(256)
void copy_past_kernel(const float4* __restrict__ past, float4* __restrict__ present4)
{
    const int idx = blockIdx.x * 256 + threadIdx.x;
    if (idx >= (B_*2*H_*P_*DEPTH_)/4) return;
    const int c = idx >> 15;
    const int r = idx & 32767;
    present4[(size_t)c * (T_*DEPTH_/4) + r] = past[idx];
}

// =====================================================================
// present f32 -> K_ws bf16 [bh][T][64] (linear) + V_ws bf16 [bh][64][T]
// =====================================================================
__global__ __launch_bounds__(256)
void prep_kv_kernel(const float* __restrict__ present,
                    ushort_t* __restrict__ Kws, ushort_t* __restrict__ Vws)
{
    __shared__ float tv[64][65];
    const int tid = threadIdx.x;
    const int kt  = blockIdx.x;
    const int bh  = blockIdx.y;
    const int b   = bh >> 4, h = bh & 15;

    const float* Kp = present + (((size_t)(b*2 + 0)*16 + h) * T_ + kt*64) * 64;
    const float* Vp = present + (((size_t)(b*2 + 1)*16 + h) * T_ + kt*64) * 64;
    ushort_t* Kd = Kws + ((size_t)bh * T_ + kt*64) * 64;

    #pragma unroll
    for (int rep = 0; rep < 4; ++rep) {
        const int idx = rep * 256 + tid;
        float4 v = ((const float4*)Kp)[idx];
        ushort4_t o;
        o[0] = f2bf(v.x); o[1] = f2bf(v.y); o[2] = f2bf(v.z); o[3] = f2bf(v.w);
        *(ushort4_t*)&Kd[idx*4] = o;
        const int r = idx >> 4, c = idx & 15;
        float4 vv = *(const float4*)&Vp[(size_t)r * 64 + c * 4];
        tv[r][c*4+0] = vv.x; tv[r][c*4+1] = vv.y;
        tv[r][c*4+2] = vv.z; tv[r][c*4+3] = vv.w;
    }
    __syncthreads();
    #pragma unroll
    for (int rep = 0; rep < 4; ++rep) {
        const int idx = rep * 256 + tid;
        const int d = idx >> 4, pg = idx & 15;
        ushort4_t o;
        o[0] = f2bf(tv[pg*4+0][d]); o[1] = f2bf(tv[pg*4+1][d]);
        o[2] = f2bf(tv[pg*4+2][d]); o[3] = f2bf(tv[pg*4+3][d]);
        *(ushort4_t*)&Vws[((size_t)bh*64 + d) * T_ + kt*64 + pg*4] = o;
    }
}

// =====================================================================
// Flash attention v3: swapped-operand MFMA, in-register softmax.
// Block = 4 waves x 16 q rows (QBLOCK=64), KVBLK=64, double-buffered
// global_load_lds staging (swizzled source), defer-max, XCD chunking.
//   QK^T: mfma(A=K, B=Q) -> S^T: lane(g,ln) reg r of subtile js holds
//         S[key=js*16+g*4+r][q=ln]  => all 64 keys of q=ln across g,js,r
//   softmax: in-lane reduce over 16 regs + shfl_xor(16,32); m,l scalar.
//   PV:   mfma(A=V^T, B=P^T) -> O^T[d][q=ln]; P via wave-private LDS
//         (4x ds_write_b64 per tile).
// =====================================================================
__global__ __launch_bounds__(256)
void attn_v3_kernel(const ushort_t* __restrict__ qin,   // [B,H,S,64] bf16 (pre-scaled)
                    const ushort_t* __restrict__ Kws,   // [bh][T][64] bf16
                    const ushort_t* __restrict__ Vws,   // [bh][64][T] bf16
                    ushort_t* __restrict__ merged)      // [B,S,D] bf16
{
    __shared__ __attribute__((aligned(16))) ushort_t Kb[2][4096];   // [64][64]
    __shared__ __attribute__((aligned(16))) ushort_t Vb[2][4096];   // V^T [64 d][64 key]
    __shared__ __attribute__((aligned(16))) ushort_t Pb[4][16][72]; // per-wave P[q][k]

    const int tid  = threadIdx.x;
    const int w    = tid >> 6;
    const int lane = tid & 63;
    const int g    = lane >> 4;
    const int ln   = lane & 15;
    const int lnm  = ln & 7;
    const int lsub = lane >> 3;                 // staged row & 7
    const int swz8 = ((lane & 7) ^ lsub) * 8;   // swizzled source granule (ushorts)

    // XCD chunking: 1024 blocks, 128 per XCD (= 4 bh); long blocks first.
    const int bid = (int)blockIdx.x;
    const int wg  = (bid & 7) * 128 + (bid >> 3);
    const int bh  = wg >> 5;
    const int q0  = (31 - (wg & 31)) * 64;
    const int b   = bh >> 4, h = bh & 15;

    const ushort_t* Kbase = Kws + (size_t)bh * T_ * 64;
    const ushort_t* Vbase = Vws + (size_t)bh * 64 * T_;
    const int nt = 33 + (q0 >> 6);

    // prologue: stage tile 0 into buf 0
    #pragma unroll
    for (int rep = 0; rep < 2; ++rep) {
        const int i = w*2 + rep;
        gload16(Kbase + (((size_t)i*8 + lsub) << 6) + swz8, &Kb[0][i*512]);
        gload16(Vbase + (size_t)(i*8 + lsub) * T_ + swz8,   &Vb[0][i*512]);
    }

    // Q B-frags: col q = ln, k = d = kh*32 + g*8 + e
    bf16x8 qf[2];
    {
        const ushort_t* Qr = qin + ((size_t)bh * S_ + q0 + w*16 + ln) * 64;
        #pragma unroll
        for (int kh = 0; kh < 2; ++kh)
            qf[kh] = __builtin_bit_cast(bf16x8, *(const short8_t*)(Qr + kh*32 + g*8));
    }

    f32x4 o[4];      // O^T: o[dsub][r] = O[d=dsub*16+g*4+r][q=ln]
    #pragma unroll
    for (int d = 0; d < 4; ++d) o[d] = (f32x4){0.f, 0.f, 0.f, 0.f};
    float m = -3.0e38f, l = 0.f;

    int buf = 0;
    for (int t = 0; t < nt; ++t) {
        asm volatile("s_waitcnt vmcnt(0)" ::: "memory");
        __builtin_amdgcn_s_barrier();
        __builtin_amdgcn_sched_barrier(0);

        if (t + 1 < nt) {
            const int t0n = (t + 1) * 64;
            #pragma unroll
            for (int rep = 0; rep < 2; ++rep) {
                const int i = w*2 + rep;
                gload16(Kbase + (((size_t)t0n + i*8 + lsub) << 6) + swz8, &Kb[buf^1][i*512]);
                gload16(Vbase + (size_t)(i*8 + lsub) * T_ + t0n + swz8,   &Vb[buf^1][i*512]);
            }
            __builtin_amdgcn_sched_barrier(0);
        }

        // ---- QK^T swapped: st[js][r] = S[key=js*16+g*4+r][q=ln] ----
        f32x4 st[4];
        #pragma unroll
        for (int js = 0; js < 4; ++js) {
            const ushort_t* kr = &Kb[buf][(js*16 + ln) * 64];
            bf16x8 a0 = __builtin_bit_cast(bf16x8, *(const short8_t*)(kr + ((    g) ^ lnm)*8));
            bf16x8 a1 = __builtin_bit_cast(bf16x8, *(const short8_t*)(kr + ((4 + g) ^ lnm)*8));
            f32x4 z = (f32x4){0.f, 0.f, 0.f, 0.f};
            z = __builtin_amdgcn_mfma_f32_16x16x32_bf16(a0, qf[0], z, 0, 0, 0);
            z = __builtin_amdgcn_mfma_f32_16x16x32_bf16(a1, qf[1], z, 0, 0, 0);
            st[js] = z;
        }

        // ---- causal mask (diagonal tile only): key kl > q row -> -inf ----
        if (t == nt - 1) {
            const int qr = w*16 + ln;
            #pragma unroll
            for (int js = 0; js < 4; ++js)
                #pragma unroll
                for (int r = 0; r < 4; ++r)
                    if (js*16 + g*4 + r > qr) st[js][r] = -1e30f;
        }

        // ---- in-lane row max + 2 shfls (all 16 q rows simultaneously) ----
        float mj[4];
        #pragma unroll
        for (int js = 0; js < 4; ++js)
            mj[js] = fmaxf(fmaxf(st[js][0], st[js][1]), fmaxf(st[js][2], st[js][3]));
        float mx = fmaxf(fmaxf(mj[0], mj[1]), fmaxf(mj[2], mj[3]));
        mx = fmaxf(mx, __shfl_xor(mx, 16));
        mx = fmaxf(mx, __shfl_xor(mx, 32));

        // ---- defer-max (T13): rescale only when max grew > 8 ----
        if (!__all(mx <= m + 8.0f)) {
            const float mnew = fmaxf(m, mx);
            const float corr = __expf(m - mnew);
            m = mnew;
            l *= corr;
            #pragma unroll
            for (int d = 0; d < 4; ++d)
                #pragma unroll
                for (int r = 0; r < 4; ++r)
                    o[d][r] *= corr;
        }

        // ---- exp, sum, pack -> wave-private Pb (P^T rows = q) ----
        float rs = 0.f;
        #pragma unroll
        for (int js = 0; js < 4; ++js) {
            float p0 = __expf(st[js][0] - m);
            float p1 = __expf(st[js][1] - m);
            float p2 = __expf(st[js][2] - m);
            float p3 = __expf(st[js][3] - m);
            rs += (p0 + p1) + (p2 + p3);
            uint2 pk;
            pk.x = (unsigned)f2bf(p0) | ((unsigned)f2bf(p1) << 16);
            pk.y = (unsigned)f2bf(p2) | ((unsigned)f2bf(p3) << 16);
            *(uint2*)&Pb[w][ln][js*16 + g*4] = pk;
        }
        rs += __shfl_xor(rs, 16);
        rs += __shfl_xor(rs, 32);
        l += rs;

        // ---- PV swapped: o[dsub] += mfma(V^T-frag, P^T-frag) ----
        #pragma unroll
        for (int kh = 0; kh < 2; ++kh) {
            bf16x8 pfr = __builtin_bit_cast(bf16x8,
                           *(const short8_t*)&Pb[w][ln][kh*32 + g*8]);
            #pragma unroll
            for (int dsub = 0; dsub < 4; ++dsub) {
                const ushort_t* vr = &Vb[buf][(dsub*16 + ln) * 64];
                bf16x8 va = __builtin_bit_cast(bf16x8,
                              *(const short8_t*)(vr + ((kh*4 + g) ^ lnm)*8));
                o[dsub] = __builtin_amdgcn_mfma_f32_16x16x32_bf16(va, pfr, o[dsub], 0, 0, 0);
            }
        }

        buf ^= 1;
    }

    // ---- epilogue: O[d][q=ln] / l -> merged[b, q, h*64+d] ----
    const float inv = 1.f / l;
    const int row = q0 + w*16 + ln;
    #pragma unroll
    for (int dsub = 0; dsub < 4; ++dsub) {
        ushort4_t ov;
        ov[0] = f2bf(o[dsub][0] * inv);
        ov[1] = f2bf(o[dsub][1] * inv);
        ov[2] = f2bf(o[dsub][2] * inv);
        ov[3] = f2bf(o[dsub][3] * inv);
        *(ushort4_t*)&merged[((size_t)b * S_ + row) * D_ + h*64 + dsub*16 + g*4] = ov;
    }
}

// =====================================================================
extern "C" void kernel_launch(void* const* d_in, const int* in_sizes, int n_in,
                              void* d_out, int out_size, void* d_ws, size_t ws_size,
                              hipStream_t stream)
{
    const float* x      = (const float*)d_in[0];
    // d_in[1] = mask: causal structure computed analytically, never read
    const float* past   = (const float*)d_in[2];
    const float* w_attn = (const float*)d_in[3];
    const float* b_attn = (const float*)d_in[4];
    const float* w_proj = (const float*)d_in[5];
    const float* b_proj = (const float*)d_in[6];

    float* out     = (float*)d_out;                    // [B,S,D]
    float* present = out + (size_t)B_ * S_ * D_;       // [B,2,H,T,64]

    // ws layout (ushorts)
    ushort_t* wsu     = (ushort_t*)d_ws;
    ushort_t* q_ws    = wsu;                  // [B,H,S,64]   8 MB
    ushort_t* mergedb = wsu + 4194304;        // [4096][1024] 8 MB
    ushort_t* wptb    = wsu + 8388608;        // [1024][1024] 2 MB
    ushort_t* xb      = wsu + 9437184;        // [4096][1024] 8 MB (dead after gemm0)
    ushort_t* watb    = wsu + 13631488;       // [3072][1024] 6 MB (dead after gemm0)
    ushort_t* K_ws    = wsu + 9437184;        // overlays xb/watb: [32][T][64] 16 MB
    ushort_t* V_ws    = wsu + 17825792;       // [32][64][T] 16 MB

    // 0) prep
    convert_bf16_kernel<<<2048, 256, 0, stream>>>(
        (const float4*)x, (ushort4_t*)xb, (B_*S_*D_)/4);
    transpose_conv_kernel<<<dim3(48, 16), 256, 0, stream>>>(w_attn, watb, 3072);
    transpose_conv_kernel<<<dim3(16, 16), 256, 0, stream>>>(w_proj, wptb, 1024);

    // 1) QKV projection; q (pre-scaled) -> bf16 ws, k/v -> present f32
    gemm_bf16_kernel<0><<<dim3(24, 32), 256, 0, stream>>>(
        xb, watb, b_attn, q_ws, present, nullptr);

    // 2) past -> present
    copy_past_kernel<<<dim3((B_*2*H_*P_*DEPTH_/4 + 255)/256), 256, 0, stream>>>(
        (const float4*)past, (float4*)present);

    // 3) present -> bf16 K_ws + V_ws^T
    prep_kv_kernel<<<dim3(64, 32), 256, 0, stream>>>(present, K_ws, V_ws);

    // 4) flash attention v3 -> merged bf16
    attn_v3_kernel<<<dim3(1024), 256, 0, stream>>>(q_ws, K_ws, V_ws, mergedb);

    // 5) output projection
    gemm_bf16_kernel<1><<<dim3(8, 32), 256, 0, stream>>>(
        mergedb, wptb, b_proj, nullptr, nullptr, out);
}

// Round 7
// 229.267 us; speedup vs baseline: 1.8562x; 1.0722x over previous
//
#include <hip/hip_runtime.h>
#include <hip/hip_bf16.h>

// Problem constants
#define B_ 2
#define S_ 2048
#define D_ 1024
#define H_ 16
#define P_ 2048
#define T_ 4096   // P_ + S_
#define DEPTH_ 64

typedef __bf16 bf16x8 __attribute__((ext_vector_type(8)));
typedef float  f32x4  __attribute__((ext_vector_type(4)));
typedef short  short8_t __attribute__((ext_vector_type(8)));
typedef unsigned short ushort_t;
typedef unsigned short ushort4_t __attribute__((ext_vector_type(4)));

// f32 -> bf16 round-to-nearest-even (cold paths)
__device__ __forceinline__ ushort_t f2bf(float f) {
    union { float f; unsigned u; } v; v.f = f;
    return (ushort_t)((v.u + 0x7fffu + ((v.u >> 16) & 1u)) >> 16);
}

// packed pair f32 -> 2x bf16 in one u32 (hot path; no builtin on gfx950)
__device__ __forceinline__ unsigned cvt_pk_bf16(float lo, float hi) {
    unsigned r;
    asm("v_cvt_pk_bf16_f32 %0, %1, %2" : "=v"(r) : "v"(lo), "v"(hi));
    return r;
}

__device__ __forceinline__ void gload16(const void* g, void* l) {
    __builtin_amdgcn_global_load_lds(
        (const __attribute__((address_space(1))) unsigned int*)g,
        (__attribute__((address_space(3))) unsigned int*)l, 16, 0, 0);
}

// =====================================================================
// x [4096][1024] f32 -> bf16
// =====================================================================
__global__ __launch_bounds__(256)
void convert_bf16_kernel(const float4* __restrict__ in, ushort4_t* __restrict__ out, int n4)
{
    for (int i = blockIdx.x * 256 + threadIdx.x; i < n4; i += gridDim.x * 256) {
        float4 v = in[i];
        ushort4_t o;
        o[0] = f2bf(v.x); o[1] = f2bf(v.y); o[2] = f2bf(v.z); o[3] = f2bf(v.w);
        out[i] = o;
    }
}

// =====================================================================
// w [K=1024][N] f32 -> wt [N][1024] bf16 (transposed)
// =====================================================================
__global__ __launch_bounds__(256)
void transpose_conv_kernel(const float* __restrict__ w, ushort_t* __restrict__ wt, int N)
{
    __shared__ float t[64][65];
    const int tid = threadIdx.x;
    const int k0 = blockIdx.y * 64, n0 = blockIdx.x * 64;
    #pragma unroll
    for (int rep = 0; rep < 4; ++rep) {
        const int idx = rep * 256 + tid;
        const int r = idx >> 4, c = idx & 15;
        float4 v = *(const float4*)&w[(size_t)(k0 + r) * N + n0 + c * 4];
        t[r][c*4+0] = v.x; t[r][c*4+1] = v.y; t[r][c*4+2] = v.z; t[r][c*4+3] = v.w;
    }
    __syncthreads();
    #pragma unroll
    for (int rep = 0; rep < 4; ++rep) {
        const int idx = rep * 256 + tid;
        const int nl = idx >> 4, kg = idx & 15;
        ushort4_t o;
        o[0] = f2bf(t[kg*4+0][nl]); o[1] = f2bf(t[kg*4+1][nl]);
        o[2] = f2bf(t[kg*4+2][nl]); o[3] = f2bf(t[kg*4+3][nl]);
        *(ushort4_t*)&wt[(size_t)(n0 + nl) * 1024 + k0 + kg*4] = o;
    }
}

// =====================================================================
// bf16 MFMA GEMM (m97 structure). MODE 0 scales q by 1/sqrt(64).
// =====================================================================
template<int MODE>
__global__ __launch_bounds__(256)
void gemm_bf16_kernel(const ushort_t* __restrict__ A,
                      const ushort_t* __restrict__ Bt,
                      const float*  __restrict__ bias,
                      ushort_t* __restrict__ out_qb,
                      float*  __restrict__ out_present,
                      float*  __restrict__ out_plain)
{
    __shared__ __attribute__((aligned(16))) ushort_t As[128*32];
    __shared__ __attribute__((aligned(16))) ushort_t Bs[128*32];

    const int tid  = threadIdx.x;
    const int w    = tid >> 6;
    const int lane = tid & 63;
    const int g    = lane >> 4;
    const int ln   = lane & 15;
    const int wr   = w >> 1, wc = w & 1;
    const int row0 = blockIdx.y * 128;
    const int col0 = blockIdx.x * 128;

    int srow[2], sgl[2];
    #pragma unroll
    for (int r = 0; r < 2; ++r) {
        const int o = (w*2 + r) * 1024 + lane * 16;
        srow[r] = o >> 6;
        const int gp = (o >> 4) & 3;
        sgl[r] = gp ^ ((srow[r] >> 1) & 3);
    }

    f32x4 acc[4][4];
    #pragma unroll
    for (int i = 0; i < 4; ++i)
        #pragma unroll
        for (int j = 0; j < 4; ++j)
            acc[i][j] = (f32x4){0.f, 0.f, 0.f, 0.f};

    for (int k0 = 0; k0 < 1024; k0 += 32) {
        #pragma unroll
        for (int r = 0; r < 2; ++r) {
            const int lb = (w*2 + r) * 512;
            gload16(&A [(size_t)(row0 + srow[r]) * 1024 + k0 + sgl[r]*8], &As[lb]);
            gload16(&Bt[(size_t)(col0 + srow[r]) * 1024 + k0 + sgl[r]*8], &Bs[lb]);
        }
        __syncthreads();

        bf16x8 af[4], bfr[4];
        #pragma unroll
        for (int i = 0; i < 4; ++i) {
            const int ra = wr*64 + i*16 + ln;
            const int ga = g ^ ((ra >> 1) & 3);
            af[i] = __builtin_bit_cast(bf16x8, *(const short8_t*)&As[ra*32 + ga*8]);
            const int rb = wc*64 + i*16 + ln;
            const int gb = g ^ ((rb >> 1) & 3);
            bfr[i] = __builtin_bit_cast(bf16x8, *(const short8_t*)&Bs[rb*32 + gb*8]);
        }
        #pragma unroll
        for (int i = 0; i < 4; ++i)
            #pragma unroll
            for (int j = 0; j < 4; ++j)
                acc[i][j] = __builtin_amdgcn_mfma_f32_16x16x32_bf16(af[i], bfr[j], acc[i][j], 0, 0, 0);
        __syncthreads();
    }

    #pragma unroll
    for (int i = 0; i < 4; ++i) {
        #pragma unroll
        for (int j = 0; j < 4; ++j) {
            const int rm = row0 + wr*64 + i*16 + g*4 + j;
            const int b  = rm >> 11;
            const int s  = rm & 2047;
            #pragma unroll
            for (int jn = 0; jn < 4; ++jn) {
                const int e = col0 + wc*64 + jn*16 + ln;
                const float v = acc[i][jn][j] + bias[e];
                if (MODE == 0) {
                    const int which = e >> 10;
                    const int f = e & 1023;
                    const int h = f >> 6, d = f & 63;
                    if (which == 0) {
                        // fold 1/sqrt(depth) into q
                        out_qb[(size_t)(((b*16 + h) * 2048 + s) << 6) + d] = f2bf(v * 0.125f);
                    } else {
                        const int kv = which - 1;
                        out_present[((((size_t)(b*2 + kv)*16 + h) * 4096 + 2048 + s) << 6) + d] = v;
                    }
                } else {
                    out_plain[(size_t)rm * 1024 + e] = v;
                }
            }
        }
    }
}

// =====================================================================
// past_layer [B,2,H,P,64] -> present[b,kv,h,0:P,:]  (fp32 linear)
// =====================================================================
__global__ __launch_bounds__(256)
void copy_past_kernel(const float4* __restrict__ past, float4* __restrict__ present4)
{
    const int idx = blockIdx.x * 256 + threadIdx.x;
    if (idx >= (B_*2*H_*P_*DEPTH_)/4) return;
    const int c = idx >> 15;
    const int r = idx & 32767;
    present4[(size_t)c * (T_*DEPTH_/4) + r] = past[idx];
}

// =====================================================================
// present f32 -> K_ws bf16 [bh][T][64] (linear) + V_ws bf16 [bh][64][T]
// =====================================================================
__global__ __launch_bounds__(256)
void prep_kv_kernel(const float* __restrict__ present,
                    ushort_t* __restrict__ Kws, ushort_t* __restrict__ Vws)
{
    __shared__ float tv[64][65];
    const int tid = threadIdx.x;
    const int kt  = blockIdx.x;
    const int bh  = blockIdx.y;
    const int b   = bh >> 4, h = bh & 15;

    const float* Kp = present + (((size_t)(b*2 + 0)*16 + h) * T_ + kt*64) * 64;
    const float* Vp = present + (((size_t)(b*2 + 1)*16 + h) * T_ + kt*64) * 64;
    ushort_t* Kd = Kws + ((size_t)bh * T_ + kt*64) * 64;

    #pragma unroll
    for (int rep = 0; rep < 4; ++rep) {
        const int idx = rep * 256 + tid;
        float4 v = ((const float4*)Kp)[idx];
        ushort4_t o;
        o[0] = f2bf(v.x); o[1] = f2bf(v.y); o[2] = f2bf(v.z); o[3] = f2bf(v.w);
        *(ushort4_t*)&Kd[idx*4] = o;
        const int r = idx >> 4, c = idx & 15;
        float4 vv = *(const float4*)&Vp[(size_t)r * 64 + c * 4];
        tv[r][c*4+0] = vv.x; tv[r][c*4+1] = vv.y;
        tv[r][c*4+2] = vv.z; tv[r][c*4+3] = vv.w;
    }
    __syncthreads();
    #pragma unroll
    for (int rep = 0; rep < 4; ++rep) {
        const int idx = rep * 256 + tid;
        const int d = idx >> 4, pg = idx & 15;
        ushort4_t o;
        o[0] = f2bf(tv[pg*4+0][d]); o[1] = f2bf(tv[pg*4+1][d]);
        o[2] = f2bf(tv[pg*4+2][d]); o[3] = f2bf(tv[pg*4+3][d]);
        *(ushort4_t*)&Vws[((size_t)bh*64 + d) * T_ + kt*64 + pg*4] = o;
    }
}

// =====================================================================
// Flash attention v4: swapped-operand MFMA, in-register softmax.
// LDS exactly 40960 B -> 4 blocks/CU (all 1024 blocks co-resident).
// Pb [16][64] with even-granule XOR swizzle (8B granule ^= (ln&7)<<1).
// Length-balanced block->qblk mapping; v_cvt_pk_bf16_f32; setprio.
// =====================================================================
__global__ __launch_bounds__(256)
void attn_v4_kernel(const ushort_t* __restrict__ qin,   // [B,H,S,64] bf16 (pre-scaled)
                    const ushort_t* __restrict__ Kws,   // [bh][T][64] bf16
                    const ushort_t* __restrict__ Vws,   // [bh][64][T] bf16
                    ushort_t* __restrict__ merged)      // [B,S,D] bf16
{
    __shared__ __attribute__((aligned(16))) ushort_t Kb[2][4096];   // [64][64]
    __shared__ __attribute__((aligned(16))) ushort_t Vb[2][4096];   // V^T [64 d][64 key]
    __shared__ __attribute__((aligned(16))) ushort_t Pb[4][16][64]; // per-wave P^T, swizzled

    const int tid  = threadIdx.x;
    const int w    = tid >> 6;
    const int lane = tid & 63;
    const int g    = lane >> 4;
    const int ln   = lane & 15;
    const int lnm  = ln & 7;
    const int lsub = lane >> 3;
    const int swz8 = ((lane & 7) ^ lsub) * 8;   // staging source granule swizzle

    // XCD chunking + complementary-length pairing: adjacent ids alternate
    // long/short so each CU's 4 resident blocks sum to ~constant work.
    const int bid  = (int)blockIdx.x;
    const int wg   = (bid & 7) * 128 + (bid >> 3);
    const int bh   = wg >> 5;
    const int kk   = wg & 31;
    const int qblk = (kk & 1) ? (31 - (kk >> 1)) : (kk >> 1);
    const int q0   = qblk * 64;
    const int b    = bh >> 4, h = bh & 15;

    const ushort_t* Kbase = Kws + (size_t)bh * T_ * 64;
    const ushort_t* Vbase = Vws + (size_t)bh * 64 * T_;
    const int nt = 33 + qblk;

    // prologue: stage tile 0 into buf 0
    #pragma unroll
    for (int rep = 0; rep < 2; ++rep) {
        const int i = w*2 + rep;
        gload16(Kbase + (((size_t)i*8 + lsub) << 6) + swz8, &Kb[0][i*512]);
        gload16(Vbase + (size_t)(i*8 + lsub) * T_ + swz8,   &Vb[0][i*512]);
    }

    // Q B-frags: col q = ln, k = d = kh*32 + g*8 + e
    bf16x8 qf[2];
    {
        const ushort_t* Qr = qin + ((size_t)bh * S_ + q0 + w*16 + ln) * 64;
        #pragma unroll
        for (int kh = 0; kh < 2; ++kh)
            qf[kh] = __builtin_bit_cast(bf16x8, *(const short8_t*)(Qr + kh*32 + g*8));
    }

    f32x4 o[4];      // O^T: o[dsub][r] = O[d=dsub*16+g*4+r][q=ln]
    #pragma unroll
    for (int d = 0; d < 4; ++d) o[d] = (f32x4){0.f, 0.f, 0.f, 0.f};
    float m = -3.0e38f, l = 0.f;

    int buf = 0;
    for (int t = 0; t < nt; ++t) {
        asm volatile("s_waitcnt vmcnt(0)" ::: "memory");
        __builtin_amdgcn_s_barrier();
        __builtin_amdgcn_sched_barrier(0);

        if (t + 1 < nt) {
            const int t0n = (t + 1) * 64;
            #pragma unroll
            for (int rep = 0; rep < 2; ++rep) {
                const int i = w*2 + rep;
                gload16(Kbase + (((size_t)t0n + i*8 + lsub) << 6) + swz8, &Kb[buf^1][i*512]);
                gload16(Vbase + (size_t)(i*8 + lsub) * T_ + t0n + swz8,   &Vb[buf^1][i*512]);
            }
            __builtin_amdgcn_sched_barrier(0);
        }

        // ---- QK^T swapped: st[js][r] = S[key=js*16+g*4+r][q=ln] ----
        f32x4 st[4];
        __builtin_amdgcn_s_setprio(1);
        #pragma unroll
        for (int js = 0; js < 4; ++js) {
            const ushort_t* kr = &Kb[buf][(js*16 + ln) * 64];
            bf16x8 a0 = __builtin_bit_cast(bf16x8, *(const short8_t*)(kr + ((    g) ^ lnm)*8));
            bf16x8 a1 = __builtin_bit_cast(bf16x8, *(const short8_t*)(kr + ((4 + g) ^ lnm)*8));
            f32x4 z = (f32x4){0.f, 0.f, 0.f, 0.f};
            z = __builtin_amdgcn_mfma_f32_16x16x32_bf16(a0, qf[0], z, 0, 0, 0);
            z = __builtin_amdgcn_mfma_f32_16x16x32_bf16(a1, qf[1], z, 0, 0, 0);
            st[js] = z;
        }
        __builtin_amdgcn_s_setprio(0);

        // ---- causal mask (diagonal tile only) ----
        if (t == nt - 1) {
            const int qr = w*16 + ln;
            #pragma unroll
            for (int js = 0; js < 4; ++js)
                #pragma unroll
                for (int r = 0; r < 4; ++r)
                    if (js*16 + g*4 + r > qr) st[js][r] = -1e30f;
        }

        // ---- in-lane row max + 2 shfls ----
        float mj[4];
        #pragma unroll
        for (int js = 0; js < 4; ++js)
            mj[js] = fmaxf(fmaxf(st[js][0], st[js][1]), fmaxf(st[js][2], st[js][3]));
        float mx = fmaxf(fmaxf(mj[0], mj[1]), fmaxf(mj[2], mj[3]));
        mx = fmaxf(mx, __shfl_xor(mx, 16));
        mx = fmaxf(mx, __shfl_xor(mx, 32));

        // ---- defer-max (T13) ----
        if (!__all(mx <= m + 8.0f)) {
            const float mnew = fmaxf(m, mx);
            const float corr = __expf(m - mnew);
            m = mnew;
            l *= corr;
            #pragma unroll
            for (int d = 0; d < 4; ++d)
                #pragma unroll
                for (int r = 0; r < 4; ++r)
                    o[d][r] *= corr;
        }

        // ---- exp, sum, packed cvt -> swizzled Pb ----
        float rs = 0.f;
        #pragma unroll
        for (int js = 0; js < 4; ++js) {
            float p0 = __expf(st[js][0] - m);
            float p1 = __expf(st[js][1] - m);
            float p2 = __expf(st[js][2] - m);
            float p3 = __expf(st[js][3] - m);
            rs += (p0 + p1) + (p2 + p3);
            uint2 pk;
            pk.x = cvt_pk_bf16(p0, p1);
            pk.y = cvt_pk_bf16(p2, p3);
            // 8B granule (js*4+g), XOR-swizzled by (lnm<<1) (even -> keeps pairs)
            *(uint2*)&Pb[w][ln][(((js*4 + g) ^ (lnm << 1)) << 2)] = pk;
        }
        rs += __shfl_xor(rs, 16);
        rs += __shfl_xor(rs, 32);
        l += rs;

        // ---- PV swapped: o[dsub] += mfma(V^T-frag, P^T-frag) ----
        __builtin_amdgcn_s_setprio(1);
        #pragma unroll
        for (int kh = 0; kh < 2; ++kh) {
            // 16B chunk (kh*4+g) ^ lnm  == granules {2c,2c+1} ^ (lnm<<1)
            bf16x8 pfr = __builtin_bit_cast(bf16x8,
                           *(const short8_t*)&Pb[w][ln][(((kh*4 + g) ^ lnm) << 3)]);
            #pragma unroll
            for (int dsub = 0; dsub < 4; ++dsub) {
                const ushort_t* vr = &Vb[buf][(dsub*16 + ln) * 64];
                bf16x8 va = __builtin_bit_cast(bf16x8,
                              *(const short8_t*)(vr + ((kh*4 + g) ^ lnm)*8));
                o[dsub] = __builtin_amdgcn_mfma_f32_16x16x32_bf16(va, pfr, o[dsub], 0, 0, 0);
            }
        }
        __builtin_amdgcn_s_setprio(0);

        buf ^= 1;
    }

    // ---- epilogue: O[d][q=ln] / l -> merged[b, q, h*64+d] ----
    const float inv = 1.f / l;
    const int row = q0 + w*16 + ln;
    #pragma unroll
    for (int dsub = 0; dsub < 4; ++dsub) {
        ushort4_t ov;
        ov[0] = f2bf(o[dsub][0] * inv);
        ov[1] = f2bf(o[dsub][1] * inv);
        ov[2] = f2bf(o[dsub][2] * inv);
        ov[3] = f2bf(o[dsub][3] * inv);
        *(ushort4_t*)&merged[((size_t)b * S_ + row) * D_ + h*64 + dsub*16 + g*4] = ov;
    }
}

// =====================================================================
extern "C" void kernel_launch(void* const* d_in, const int* in_sizes, int n_in,
                              void* d_out, int out_size, void* d_ws, size_t ws_size,
                              hipStream_t stream)
{
    const float* x      = (const float*)d_in[0];
    // d_in[1] = mask: causal structure computed analytically, never read
    const float* past   = (const float*)d_in[2];
    const float* w_attn = (const float*)d_in[3];
    const float* b_attn = (const float*)d_in[4];
    const float* w_proj = (const float*)d_in[5];
    const float* b_proj = (const float*)d_in[6];

    float* out     = (float*)d_out;                    // [B,S,D]
    float* present = out + (size_t)B_ * S_ * D_;       // [B,2,H,T,64]

    // ws layout (ushorts)
    ushort_t* wsu     = (ushort_t*)d_ws;
    ushort_t* q_ws    = wsu;                  // [B,H,S,64]   8 MB
    ushort_t* mergedb = wsu + 4194304;        // [4096][1024] 8 MB
    ushort_t* wptb    = wsu + 8388608;        // [1024][1024] 2 MB
    ushort_t* xb      = wsu + 9437184;        // [4096][1024] 8 MB (dead after gemm0)
    ushort_t* watb    = wsu + 13631488;       // [3072][1024] 6 MB (dead after gemm0)
    ushort_t* K_ws    = wsu + 9437184;        // overlays xb/watb: [32][T][64] 16 MB
    ushort_t* V_ws    = wsu + 17825792;       // [32][64][T] 16 MB

    // 0) prep
    convert_bf16_kernel<<<2048, 256, 0, stream>>>(
        (const float4*)x, (ushort4_t*)xb, (B_*S_*D_)/4);
    transpose_conv_kernel<<<dim3(48, 16), 256, 0, stream>>>(w_attn, watb, 3072);
    transpose_conv_kernel<<<dim3(16, 16), 256, 0, stream>>>(w_proj, wptb, 1024);

    // 1) QKV projection; q (pre-scaled) -> bf16 ws, k/v -> present f32
    gemm_bf16_kernel<0><<<dim3(24, 32), 256, 0, stream>>>(
        xb, watb, b_attn, q_ws, present, nullptr);

    // 2) past -> present
    copy_past_kernel<<<dim3((B_*2*H_*P_*DEPTH_/4 + 255)/256), 256, 0, stream>>>(
        (const float4*)past, (float4*)present);

    // 3) present -> bf16 K_ws + V_ws^T
    prep_kv_kernel<<<dim3(64, 32), 256, 0, stream>>>(present, K_ws, V_ws);

    // 4) flash attention v4 -> merged bf16
    attn_v4_kernel<<<dim3(1024), 256, 0, stream>>>(q_ws, K_ws, V_ws, mergedb);

    // 5) output projection
    gemm_bf16_kernel<1><<<dim3(8, 32), 256, 0, stream>>>(
        mergedb, wptb, b_proj, nullptr, nullptr, out);
}